// Round 20
// baseline (3015.649 us; speedup 1.0000x reference)
//
#include <hip/hip_runtime.h>

// ---------------------------------------------------------------------------
// ViT forward on MI355X. bf16 MFMA GEMMs (2-phase double-buffered, XCD-swizzled
// 1D grid) + fused flash attn v8 (8-wave, 144 blocks — measured best).
// ---------------------------------------------------------------------------

typedef unsigned short u16;
typedef __bf16 bf16v8 __attribute__((ext_vector_type(8)));
typedef float f32v4 __attribute__((ext_vector_type(4)));
typedef float f32x16 __attribute__((ext_vector_type(16)));

#define NTOK   4608
#define TTOT   9216
#define DIMD   1024
#define H3     3072
#define MLPH   4096
#define NHEAD  4
#define DHEAD  256
#define NLAYER 4
#define KVB    32
#define NKT    (NTOK / KVB)   // 144

__device__ __forceinline__ u16 f2bf(float f) {
  unsigned u = __float_as_uint(f);
  u += 0x7fffu + ((u >> 16) & 1u);   // RNE
  return (u16)(u >> 16);
}
__device__ __forceinline__ float bf2f(u16 b) {
  return __uint_as_float(((unsigned)b) << 16);
}
__device__ __forceinline__ void gload16(const void* g, void* l) {
  __builtin_amdgcn_global_load_lds((__attribute__((address_space(1))) void*)g,
                                   (__attribute__((address_space(3))) void*)l,
                                   16, 0, 0);
}

// ---------------- weight transpose fp32(R,C) -> bf16(C,R) ----------------
__global__ __launch_bounds__(256) void transpose_w(
    const float* __restrict__ src, u16* __restrict__ dst, int R, int C) {
  __shared__ float tile[32][33];
  const int c0 = blockIdx.x * 32, r0 = blockIdx.y * 32;
  const int tx = threadIdx.x, ty = threadIdx.y;
#pragma unroll
  for (int i = 0; i < 32; i += 8)
    tile[ty + i][tx] = src[(size_t)(r0 + ty + i) * C + c0 + tx];
  __syncthreads();
#pragma unroll
  for (int i = 0; i < 32; i += 8)
    dst[(size_t)(c0 + ty + i) * R + r0 + tx] = f2bf(tile[tx][ty + i]);
}

__global__ __launch_bounds__(256) void convert_bf16(
    const float* __restrict__ src, u16* __restrict__ dst, int n) {
  int i = blockIdx.x * 256 + threadIdx.x;
  if (i < n) dst[i] = f2bf(src[i]);
}

// ---------------- patch extraction: img -> A[9216][256] bf16 ----------------
__global__ __launch_bounds__(256) void patch_extract(
    const float* __restrict__ img, u16* __restrict__ A) {
  const int t = blockIdx.x;
  const int k = threadIdx.x;
  const int b = t / NTOK, r = t % NTOK;
  const int d = r / 576, r2 = r % 576;
  const int hh = r2 / 24, ww = r2 % 24;
  const int ci = k >> 7, k2 = k & 127;
  const int kd = k2 >> 6, k3 = k2 & 63;
  const int kh = k3 >> 3, kw = k3 & 7;
  const size_t idx =
      ((size_t)((b * 2 + ci) * 16 + (2 * d + kd))) * (192 * 192) +
      (size_t)(8 * hh + kh) * 192 + (8 * ww + kw);
  A[(size_t)t * 256 + k] = f2bf(img[idx]);
}

// ---------------- LayerNorm (row=1024). OUTF32: 1 -> fp32, 0 -> bf16 --------
template <int OUTF32>
__global__ __launch_bounds__(256) void ln_kernel(
    const float* __restrict__ x, const float* __restrict__ g,
    const float* __restrict__ bta, void* __restrict__ out) {
  const size_t row = blockIdx.x;
  const int t = threadIdx.x;
  const float4 v = ((const float4*)(x + row * DIMD))[t];
  float s = v.x + v.y + v.z + v.w;
  float ss = v.x * v.x + v.y * v.y + v.z * v.z + v.w * v.w;
#pragma unroll
  for (int o = 32; o; o >>= 1) {
    s += __shfl_xor(s, o, 64);
    ss += __shfl_xor(ss, o, 64);
  }
  __shared__ float sh[8];
  if ((t & 63) == 0) { sh[t >> 6] = s; sh[4 + (t >> 6)] = ss; }
  __syncthreads();
  s = sh[0] + sh[1] + sh[2] + sh[3];
  ss = sh[4] + sh[5] + sh[6] + sh[7];
  const float mu = s * (1.f / DIMD);
  const float rs = rsqrtf(ss * (1.f / DIMD) - mu * mu + 1e-5f);
  const float4 gg = ((const float4*)g)[t];
  const float4 bb = ((const float4*)bta)[t];
  const float y0 = (v.x - mu) * rs * gg.x + bb.x;
  const float y1 = (v.y - mu) * rs * gg.y + bb.y;
  const float y2 = (v.z - mu) * rs * gg.z + bb.z;
  const float y3 = (v.w - mu) * rs * gg.w + bb.w;
  if (OUTF32) {
    float4 o4; o4.x = y0; o4.y = y1; o4.z = y2; o4.w = y3;
    ((float4*)out)[row * 256 + t] = o4;
  } else {
    ushort4 o4;
    o4.x = f2bf(y0); o4.y = f2bf(y1); o4.z = f2bf(y2); o4.w = f2bf(y3);
    ((ushort4*)out)[row * 256 + t] = o4;
  }
}

// ---------------- transpose V slice of qkv -> vT[b][h][256][4608] -----------
__global__ __launch_bounds__(256) void transpose_v(
    const u16* __restrict__ qkv, u16* __restrict__ vT) {
  const int bh = blockIdx.z, b = bh >> 2, h = bh & 3;
  const u16* src = qkv + (size_t)b * NTOK * H3 + 2048 + h * DHEAD;
  u16* dst = vT + (size_t)bh * DHEAD * NTOK;
  __shared__ u16 tile[32][33];
  const int t0 = blockIdx.x * 32, d0 = blockIdx.y * 32;
  const int tx = threadIdx.x, ty = threadIdx.y;
#pragma unroll
  for (int i = 0; i < 32; i += 8)
    tile[ty + i][tx] = src[(size_t)(t0 + ty + i) * H3 + d0 + tx];
  __syncthreads();
#pragma unroll
  for (int i = 0; i < 32; i += 8)
    dst[(size_t)(d0 + ty + i) * NTOK + t0 + tx] = tile[tx][ty + i];
}

// ---------------------------------------------------------------------------
// Fused flash attention v8 (measured best: 333 us/launch).
// Grid: 144 = 18 qtiles x 8 bh. 512 thr = 8 waves; wave owns 32 q-rows
// (q-row = lane&31 = c; partner c^32 shares the row). KVB=32, double-buffered
// K[32][512B] + V[128][128B] (row rr = d=rr|d=rr+128), XOR swizzle
// ((row&7)<<4) via pre-swizzled global source (rule 21).
// ---------------------------------------------------------------------------
__global__ __launch_bounds__(512, 2) void flash_attn(
    const u16* __restrict__ qkv, const u16* __restrict__ vT,
    u16* __restrict__ obuf) {
  __shared__ __align__(16) u16 Ks[2][KVB * 256];  // 16 KB each
  __shared__ __align__(16) u16 Vs[2][128 * 64];   // 16 KB each

  const int tid = threadIdx.x;
  const int lane = tid & 63, w = tid >> 6;
  const int c = lane & 31, h32 = lane >> 5;
  const int bh = blockIdx.x & 7, b = bh >> 2, h = bh & 3;
  const int t0 = (blockIdx.x >> 3) * 256;

  const u16* qkv_b = qkv + (size_t)b * NTOK * H3;
  const u16* vt_bh = vT + (size_t)bh * (size_t)DHEAD * NTOK;
  const int kcol = DIMD + h * DHEAD;
  const int csw = (c & 7) << 4;

  // Q B-frags: qf[ks] = Q[t0+w*32+c][ks*16 + h32*8 .. +7]
  bf16v8 qf[16];
  {
    const u16* qrow = qkv_b + (size_t)(t0 + w * 32 + c) * H3 + h * DHEAD + h32 * 8;
#pragma unroll
    for (int ks = 0; ks < 16; ks++)
      qf[ks] = *reinterpret_cast<const bf16v8*>(qrow + ks * 16);
  }

  f32x16 o[8];
#pragma unroll
  for (int dt = 0; dt < 8; dt++)
#pragma unroll
    for (int r = 0; r < 16; r++) o[dt][r] = 0.f;
  float m = -1e30f, l = 0.f;

  auto stage = [&](int kt) {
    const int buf = kt & 1;
    const int kt0 = kt * KVB;
    // K: 32 rows x 512B = 1024 chunks
#pragma unroll
    for (int i = 0; i < 2; i++) {
      const int q = i * 512 + tid;
      const int row = q >> 5;
      const int cb = ((q & 31) * 16) ^ ((row & 7) << 4);
      gload16(qkv_b + (size_t)(kt0 + row) * H3 + kcol + (cb >> 1),
              (char*)&Ks[buf][0] + (size_t)q * 16);
    }
    // V: 128 rows x 128B; row rr = {d=rr | d=rr+128} x 32 toks
#pragma unroll
    for (int i = 0; i < 2; i++) {
      const int q = i * 512 + tid;
      const int rr = q >> 3;
      const int p = ((q & 7) * 16) ^ ((rr & 7) << 4);
      const int d = rr + ((p >> 6) << 7);
      gload16(vt_bh + (size_t)d * NTOK + kt0 + ((p & 63) >> 1),
              (char*)&Vs[buf][0] + (size_t)q * 16);
    }
  };

  stage(0);

  for (int kt = 0; kt < NKT; kt++) {
    __syncthreads();            // tile kt staged; all waves done with kt-1
    if (kt + 1 < NKT) stage(kt + 1);

    const char* kb = (const char*)&Ks[kt & 1][0];
    const char* vb = (const char*)&Vs[kt & 1][0];

    // ---- S^T = K Q^T : lane holds 16 of 32 scores for q-row c ----
    f32x16 st;
#pragma unroll
    for (int r = 0; r < 16; r++) st[r] = 0.f;
    const char* krow = kb + c * 512;
    __builtin_amdgcn_s_setprio(1);
#pragma unroll
    for (int ks = 0; ks < 16; ks++) {
      const bf16v8 kf =
          *reinterpret_cast<const bf16v8*>(krow + ((ks * 32 + h32 * 16) ^ csw));
      st = __builtin_amdgcn_mfma_f32_32x32x16_bf16(kf, qf[ks], st, 0, 0, 0);
    }
    __builtin_amdgcn_s_setprio(0);

    // ---- lane-local online softmax (defer-max THR=8) ----
    float mx = st[0];
#pragma unroll
    for (int r = 1; r < 16; r++) mx = fmaxf(mx, st[r]);
    mx = fmaxf(mx, __shfl_xor(mx, 32, 64));
    const float pm = mx * 0.03125f;
    if (__any(pm > m + 8.f)) {
      const float mn = fmaxf(m, pm);
      const float corr = __expf(m - mn);
      m = mn; l *= corr;
#pragma unroll
      for (int dt = 0; dt < 8; dt++)
#pragma unroll
        for (int r = 0; r < 16; r++) o[dt][r] *= corr;
    }
    float sum = 0.f;
#pragma unroll
    for (int r = 0; r < 16; r++) {
      const float p = __expf(st[r] * 0.03125f - m);
      st[r] = p; sum += p;
    }
    sum += __shfl_xor(sum, 32, 64);
    l += sum;

    // ---- P -> bf16 B-frags (lane^32 exchange) + PV ----
#pragma unroll
    for (int s = 0; s < 2; s++) {
      const int rb = s * 8;
      float z[4];
#pragma unroll
      for (int k = 0; k < 4; k++) {
        const float y = h32 ? st[rb + k] : st[rb + 4 + k];  // send partner's need
        z[k] = __shfl_xor(y, 32, 64);
      }
      union { u16 u[8]; bf16v8 v; } pb;
#pragma unroll
      for (int k = 0; k < 4; k++) {
        pb.u[k]     = f2bf(h32 ? z[k] : st[rb + k]);
        pb.u[4 + k] = f2bf(h32 ? st[rb + 4 + k] : z[k]);
      }

      __builtin_amdgcn_s_setprio(1);
#pragma unroll
      for (int dt = 0; dt < 8; dt++) {
        const int rr = (dt & 3) * 32 + c;
        const int byte = (((dt >> 2) * 64 + s * 32 + h32 * 16)) ^ csw;
        const bf16v8 vf = *reinterpret_cast<const bf16v8*>(vb + rr * 128 + byte);
        o[dt] = __builtin_amdgcn_mfma_f32_32x32x16_bf16(vf, pb.v, o[dt], 0, 0, 0);
      }
      __builtin_amdgcn_s_setprio(0);
    }
  }

  // ---- epilogue: O^T/l -> obuf ----
  const float rl = 1.f / l;
  u16* orow = obuf + (size_t)(b * NTOK + t0 + w * 32 + c) * DIMD + h * DHEAD;
#pragma unroll
  for (int dt = 0; dt < 8; dt++) {
#pragma unroll
    for (int rq = 0; rq < 4; rq++) {
      ushort4 v4;
      v4.x = f2bf(o[dt][rq * 4 + 0] * rl);
      v4.y = f2bf(o[dt][rq * 4 + 1] * rl);
      v4.z = f2bf(o[dt][rq * 4 + 2] * rl);
      v4.w = f2bf(o[dt][rq * 4 + 3] * rl);
      *reinterpret_cast<ushort4*>(orow + dt * 32 + rq * 8 + h32 * 4) = v4;
    }
  }
}

// ---------------- GEMM v3: 2-phase dbuf + XCD-swizzled 1D grid --------------
// grid = gm*gn blocks (1D). XCD remap: work = (id%8)*(nwg/8) + id/8
// (bijective, nwg%8==0 for all our launches); bm = work % gm (fastest) so an
// XCD's contiguous work chunk walks A-tiles while reusing few B-panels in its
// private L2. EPI: 0 bf16; 2 fp32 resid+=; 3 gelu; 4 conv epilogue.
template <int EPI>
__global__ __launch_bounds__(256) void gemm_bt(
    const u16* __restrict__ A, int lda,
    const u16* __restrict__ Bt, int ldb,
    int K, void* __restrict__ Cp, int ldc,
    const float* __restrict__ bias, const float* __restrict__ extra,
    int gm) {
  __shared__ __align__(16) u16 As[2][128 * 32];
  __shared__ __align__(16) u16 Bs[2][128 * 32];
  const int tid = threadIdx.x;
  const int nwg = gridDim.x;
  const int cpx = nwg >> 3;
  const int work = (blockIdx.x & 7) * cpx + (blockIdx.x >> 3);
  const int bm = work % gm, bn = work / gm;

  const int c0 = tid, c1 = tid + 256;
  const u16* Ab = A + (size_t)(bm * 128) * lda;
  const u16* Bb = Bt + (size_t)(bn * 128) * ldb;
  const size_t a0 = (size_t)(c0 >> 2) * lda + (c0 & 3) * 8;
  const size_t a1 = (size_t)(c1 >> 2) * lda + (c1 & 3) * 8;
  const size_t b0 = (size_t)(c0 >> 2) * ldb + (c0 & 3) * 8;
  const size_t b1 = (size_t)(c1 >> 2) * ldb + (c1 & 3) * 8;

  const int lane = tid & 63;
  const int wv = tid >> 6;
  const int wm = (wv >> 1) * 64;
  const int wn = (wv & 1) * 64;
  const int fr = lane & 15;
  const int fk = (lane >> 4) * 8;

  auto stage = [&](int k0, int buf) {
    gload16(Ab + a0 + k0, &As[buf][0] + (size_t)c0 * 8);
    gload16(Ab + a1 + k0, &As[buf][0] + (size_t)c1 * 8);
    gload16(Bb + b0 + k0, &Bs[buf][0] + (size_t)c0 * 8);
    gload16(Bb + b1 + k0, &Bs[buf][0] + (size_t)c1 * 8);
  };

  f32v4 acc[4][4];
#pragma unroll
  for (int m = 0; m < 4; m++)
#pragma unroll
    for (int n = 0; n < 4; n++) acc[m][n] = (f32v4){0.f, 0.f, 0.f, 0.f};

  stage(0, 0);
  __syncthreads();               // tile 0 resident

  int buf = 0;
  for (int k0 = 0; k0 < K; k0 += 32) {
    if (k0 + 32 < K) stage(k0 + 32, buf ^ 1);   // prefetch overlaps MFMA

    bf16v8 af[4], bq[4];
#pragma unroll
    for (int m = 0; m < 4; m++)
      af[m] = *reinterpret_cast<const bf16v8*>(&As[buf][(wm + m * 16 + fr) * 32 + fk]);
#pragma unroll
    for (int n = 0; n < 4; n++)
      bq[n] = *reinterpret_cast<const bf16v8*>(&Bs[buf][(wn + n * 16 + fr) * 32 + fk]);
#pragma unroll
    for (int m = 0; m < 4; m++)
#pragma unroll
      for (int n = 0; n < 4; n++)
        acc[m][n] =
            __builtin_amdgcn_mfma_f32_16x16x32_bf16(af[m], bq[n], acc[m][n], 0, 0, 0);

    __syncthreads();             // drains prefetch; next iter reads buf^1
    buf ^= 1;
  }

  const int rbase = bm * 128 + wm + (lane >> 4) * 4;
  const int cbase = bn * 128 + wn + fr;
#pragma unroll
  for (int m = 0; m < 4; m++) {
#pragma unroll
    for (int n = 0; n < 4; n++) {
      const int col = cbase + n * 16;
#pragma unroll
      for (int j = 0; j < 4; j++) {
        const int rowi = rbase + m * 16 + j;
        const float v = acc[m][n][j];
        if (EPI == 0) {
          ((u16*)Cp)[(size_t)rowi * ldc + col] = f2bf(v);
        } else if (EPI == 2) {
          float* p = (float*)Cp + (size_t)rowi * ldc + col;
          *p += v + bias[col];
        } else if (EPI == 3) {
          float t = v + bias[col];
          t = 0.5f * t * (1.f + erff(t * 0.70710678118654752f));
          ((u16*)Cp)[(size_t)rowi * ldc + col] = f2bf(t);
        } else {
          ((float*)Cp)[(size_t)rowi * ldc + col] =
              v + bias[col] + extra[(size_t)(rowi % NTOK) * DIMD + col];
        }
      }
    }
  }
}

// ---------------------------------------------------------------------------
// workspace layout (bytes) — peak ~158 MB
// ---------------------------------------------------------------------------
#define SZ_QKVT ((size_t)H3 * DIMD * 2)
#define SZ_OUTT ((size_t)DIMD * DIMD * 2)
#define SZ_FC1T ((size_t)MLPH * DIMD * 2)
#define SZ_FC2T ((size_t)DIMD * MLPH * 2)
#define SZ_CONVW ((size_t)DIMD * 256 * 2)
#define SZ_X ((size_t)TTOT * DIMD * 4)
#define SZ_XO ((size_t)TTOT * DIMD * 2)            // x1 | obuf
#define SZ_BIGA ((size_t)TTOT * H3 * 2 + (size_t)8 * DHEAD * NTOK * 2) // qkv+vT | hbuf | patchA

#define OFF_QKVT ((size_t)0)
#define OFF_OUTT (OFF_QKVT + SZ_QKVT)
#define OFF_FC1T (OFF_OUTT + SZ_OUTT)
#define OFF_FC2T (OFF_FC1T + SZ_FC1T)
#define OFF_CONVW (OFF_FC2T + SZ_FC2T)
#define OFF_X (OFF_CONVW + SZ_CONVW)
#define OFF_XO (OFF_X + SZ_X)
#define OFF_BIGA (OFF_XO + SZ_XO)
#define WS_NEED (OFF_BIGA + SZ_BIGA)

extern "C" void kernel_launch(void* const* d_in, const int* in_sizes, int n_in,
                              void* d_out, int out_size, void* d_ws, size_t ws_size,
                              hipStream_t stream) {
  const float* img = (const float*)d_in[0];
  const float* conv_w = (const float*)d_in[1];
  const float* conv_b = (const float*)d_in[2];
  const float* pos = (const float*)d_in[3];
  const float* ln1_g = (const float*)d_in[4];
  const float* ln1_b = (const float*)d_in[5];
  const float* qkv_w = (const float*)d_in[6];
  const float* out_w = (const float*)d_in[7];
  const float* out_b = (const float*)d_in[8];
  const float* ln2_g = (const float*)d_in[9];
  const float* ln2_b = (const float*)d_in[10];
  const float* fc1_w = (const float*)d_in[11];
  const float* fc1_b = (const float*)d_in[12];
  const float* fc2_w = (const float*)d_in[13];
  const float* fc2_b = (const float*)d_in[14];
  const float* lnf_g = (const float*)d_in[15];
  const float* lnf_b = (const float*)d_in[16];
  float* out = (float*)d_out;

  if (ws_size < WS_NEED) return;

  char* ws = (char*)d_ws;
  u16* qkvT = (u16*)(ws + OFF_QKVT);
  u16* outT = (u16*)(ws + OFF_OUTT);
  u16* fc1T = (u16*)(ws + OFF_FC1T);
  u16* fc2T = (u16*)(ws + OFF_FC2T);
  u16* convW = (u16*)(ws + OFF_CONVW);
  float* x = (float*)(ws + OFF_X);
  u16* x1 = (u16*)(ws + OFF_XO);
  u16* obuf = (u16*)(ws + OFF_XO);     // aliased with x1 (disjoint lifetime)
  u16* qkv = (u16*)(ws + OFF_BIGA);
  u16* vT = (u16*)(ws + OFF_BIGA + (size_t)TTOT * H3 * 2);
  u16* hbuf = (u16*)(ws + OFF_BIGA);   // aliased (MLP phase)
  u16* patchA = (u16*)(ws + OFF_BIGA); // aliased (pre-layer phase)

  const dim3 tb(32, 8);

  // ---- patch embed ----
  convert_bf16<<<1024, 256, 0, stream>>>(conv_w, convW, DIMD * 256);
  patch_extract<<<TTOT, 256, 0, stream>>>(img, patchA);
  gemm_bt<4><<<dim3(72 * 8, 1, 1), 256, 0, stream>>>(
      patchA, 256, convW, 256, 256, x, DIMD, conv_b, pos, 72);

  for (int l = 0; l < NLAYER; l++) {
    transpose_w<<<dim3(H3 / 32, DIMD / 32, 1), tb, 0, stream>>>(
        qkv_w + (size_t)l * DIMD * H3, qkvT, DIMD, H3);
    transpose_w<<<dim3(DIMD / 32, DIMD / 32, 1), tb, 0, stream>>>(
        out_w + (size_t)l * DIMD * DIMD, outT, DIMD, DIMD);
    transpose_w<<<dim3(MLPH / 32, DIMD / 32, 1), tb, 0, stream>>>(
        fc1_w + (size_t)l * DIMD * MLPH, fc1T, DIMD, MLPH);
    transpose_w<<<dim3(DIMD / 32, MLPH / 32, 1), tb, 0, stream>>>(
        fc2_w + (size_t)l * MLPH * DIMD, fc2T, MLPH, DIMD);

    // LN1 -> x1 (bf16)
    ln_kernel<0><<<TTOT, 256, 0, stream>>>(x, ln1_g + l * DIMD, ln1_b + l * DIMD, x1);
    // QKV
    gemm_bt<0><<<dim3(72 * 24, 1, 1), 256, 0, stream>>>(
        x1, DIMD, qkvT, DIMD, DIMD, qkv, H3, nullptr, nullptr, 72);
    // V -> vT
    transpose_v<<<dim3(NTOK / 32, DHEAD / 32, 8), tb, 0, stream>>>(qkv, vT);

    // fused attention -> obuf
    flash_attn<<<dim3(18 * 8, 1, 1), 512, 0, stream>>>(qkv, vT, obuf);

    // x += o @ out_w + out_b
    gemm_bt<2><<<dim3(72 * 8, 1, 1), 256, 0, stream>>>(
        obuf, DIMD, outT, DIMD, DIMD, x, DIMD, out_b + l * DIMD, nullptr, 72);
    // LN2 -> x1
    ln_kernel<0><<<TTOT, 256, 0, stream>>>(x, ln2_g + l * DIMD, ln2_b + l * DIMD, x1);
    // h = gelu(x1 @ fc1 + b)
    gemm_bt<3><<<dim3(72 * 32, 1, 1), 256, 0, stream>>>(
        x1, DIMD, fc1T, DIMD, DIMD, hbuf, MLPH, fc1_b + l * MLPH, nullptr, 72);
    // x += h @ fc2 + b
    gemm_bt<2><<<dim3(72 * 8, 1, 1), 256, 0, stream>>>(
        hbuf, MLPH, fc2T, MLPH, MLPH, x, DIMD, fc2_b + l * DIMD, nullptr, 72);
  }

  ln_kernel<1><<<TTOT, 256, 0, stream>>>(x, lnf_g, lnf_b, out);
}

// Round 21
// 2865.090 us; speedup vs baseline: 1.0525x; 1.0525x over previous
//
#include <hip/hip_runtime.h>

// ---------------------------------------------------------------------------
// ViT forward on MI355X. bf16 MFMA GEMMs (2-phase double-buffered) + fused
// flash attn v8: swapped 32x32x16, lane-local softmax, P in regs, KVB=32,
// 8-wave blocks, shfl_xor(32) cross-lane. (= Round-18 measured best.)
// ---------------------------------------------------------------------------

typedef unsigned short u16;
typedef __bf16 bf16v8 __attribute__((ext_vector_type(8)));
typedef float f32v4 __attribute__((ext_vector_type(4)));
typedef float f32x16 __attribute__((ext_vector_type(16)));

#define NTOK   4608
#define TTOT   9216
#define DIMD   1024
#define H3     3072
#define MLPH   4096
#define NHEAD  4
#define DHEAD  256
#define NLAYER 4
#define KVB    32
#define NKT    (NTOK / KVB)   // 144

__device__ __forceinline__ u16 f2bf(float f) {
  unsigned u = __float_as_uint(f);
  u += 0x7fffu + ((u >> 16) & 1u);   // RNE
  return (u16)(u >> 16);
}
__device__ __forceinline__ float bf2f(u16 b) {
  return __uint_as_float(((unsigned)b) << 16);
}
__device__ __forceinline__ void gload16(const void* g, void* l) {
  __builtin_amdgcn_global_load_lds((__attribute__((address_space(1))) void*)g,
                                   (__attribute__((address_space(3))) void*)l,
                                   16, 0, 0);
}

// ---------------- weight transpose fp32(R,C) -> bf16(C,R) ----------------
__global__ __launch_bounds__(256) void transpose_w(
    const float* __restrict__ src, u16* __restrict__ dst, int R, int C) {
  __shared__ float tile[32][33];
  const int c0 = blockIdx.x * 32, r0 = blockIdx.y * 32;
  const int tx = threadIdx.x, ty = threadIdx.y;
#pragma unroll
  for (int i = 0; i < 32; i += 8)
    tile[ty + i][tx] = src[(size_t)(r0 + ty + i) * C + c0 + tx];
  __syncthreads();
#pragma unroll
  for (int i = 0; i < 32; i += 8)
    dst[(size_t)(c0 + ty + i) * R + r0 + tx] = f2bf(tile[tx][ty + i]);
}

__global__ __launch_bounds__(256) void convert_bf16(
    const float* __restrict__ src, u16* __restrict__ dst, int n) {
  int i = blockIdx.x * 256 + threadIdx.x;
  if (i < n) dst[i] = f2bf(src[i]);
}

// ---------------- patch extraction: img -> A[9216][256] bf16 ----------------
__global__ __launch_bounds__(256) void patch_extract(
    const float* __restrict__ img, u16* __restrict__ A) {
  const int t = blockIdx.x;
  const int k = threadIdx.x;
  const int b = t / NTOK, r = t % NTOK;
  const int d = r / 576, r2 = r % 576;
  const int hh = r2 / 24, ww = r2 % 24;
  const int ci = k >> 7, k2 = k & 127;
  const int kd = k2 >> 6, k3 = k2 & 63;
  const int kh = k3 >> 3, kw = k3 & 7;
  const size_t idx =
      ((size_t)((b * 2 + ci) * 16 + (2 * d + kd))) * (192 * 192) +
      (size_t)(8 * hh + kh) * 192 + (8 * ww + kw);
  A[(size_t)t * 256 + k] = f2bf(img[idx]);
}

// ---------------- LayerNorm (row=1024). OUTF32: 1 -> fp32, 0 -> bf16 --------
template <int OUTF32>
__global__ __launch_bounds__(256) void ln_kernel(
    const float* __restrict__ x, const float* __restrict__ g,
    const float* __restrict__ bta, void* __restrict__ out) {
  const size_t row = blockIdx.x;
  const int t = threadIdx.x;
  const float4 v = ((const float4*)(x + row * DIMD))[t];
  float s = v.x + v.y + v.z + v.w;
  float ss = v.x * v.x + v.y * v.y + v.z * v.z + v.w * v.w;
#pragma unroll
  for (int o = 32; o; o >>= 1) {
    s += __shfl_xor(s, o, 64);
    ss += __shfl_xor(ss, o, 64);
  }
  __shared__ float sh[8];
  if ((t & 63) == 0) { sh[t >> 6] = s; sh[4 + (t >> 6)] = ss; }
  __syncthreads();
  s = sh[0] + sh[1] + sh[2] + sh[3];
  ss = sh[4] + sh[5] + sh[6] + sh[7];
  const float mu = s * (1.f / DIMD);
  const float rs = rsqrtf(ss * (1.f / DIMD) - mu * mu + 1e-5f);
  const float4 gg = ((const float4*)g)[t];
  const float4 bb = ((const float4*)bta)[t];
  const float y0 = (v.x - mu) * rs * gg.x + bb.x;
  const float y1 = (v.y - mu) * rs * gg.y + bb.y;
  const float y2 = (v.z - mu) * rs * gg.z + bb.z;
  const float y3 = (v.w - mu) * rs * gg.w + bb.w;
  if (OUTF32) {
    float4 o4; o4.x = y0; o4.y = y1; o4.z = y2; o4.w = y3;
    ((float4*)out)[row * 256 + t] = o4;
  } else {
    ushort4 o4;
    o4.x = f2bf(y0); o4.y = f2bf(y1); o4.z = f2bf(y2); o4.w = f2bf(y3);
    ((ushort4*)out)[row * 256 + t] = o4;
  }
}

// ---------------- transpose V slice of qkv -> vT[b][h][256][4608] -----------
__global__ __launch_bounds__(256) void transpose_v(
    const u16* __restrict__ qkv, u16* __restrict__ vT) {
  const int bh = blockIdx.z, b = bh >> 2, h = bh & 3;
  const u16* src = qkv + (size_t)b * NTOK * H3 + 2048 + h * DHEAD;
  u16* dst = vT + (size_t)bh * DHEAD * NTOK;
  __shared__ u16 tile[32][33];
  const int t0 = blockIdx.x * 32, d0 = blockIdx.y * 32;
  const int tx = threadIdx.x, ty = threadIdx.y;
#pragma unroll
  for (int i = 0; i < 32; i += 8)
    tile[ty + i][tx] = src[(size_t)(t0 + ty + i) * H3 + d0 + tx];
  __syncthreads();
#pragma unroll
  for (int i = 0; i < 32; i += 8)
    dst[(size_t)(d0 + ty + i) * NTOK + t0 + tx] = tile[tx][ty + i];
}

// ---------------------------------------------------------------------------
// Fused flash attention v8 (measured best: 333 us/launch).
// Grid: 144 = 18 qtiles x 8 bh. 512 thr = 8 waves; wave owns 32 q-rows
// (q-row = lane&31 = c; partner c^32 shares the row). KVB=32, double-buffered
// K[32][512B] + V[128][128B] (row rr = d=rr|d=rr+128), XOR swizzle
// ((row&7)<<4) via pre-swizzled global source (rule 21).
// ---------------------------------------------------------------------------
__global__ __launch_bounds__(512, 2) void flash_attn(
    const u16* __restrict__ qkv, const u16* __restrict__ vT,
    u16* __restrict__ obuf) {
  __shared__ __align__(16) u16 Ks[2][KVB * 256];  // 16 KB each
  __shared__ __align__(16) u16 Vs[2][128 * 64];   // 16 KB each

  const int tid = threadIdx.x;
  const int lane = tid & 63, w = tid >> 6;
  const int c = lane & 31, h32 = lane >> 5;
  const int bh = blockIdx.x & 7, b = bh >> 2, h = bh & 3;
  const int t0 = (blockIdx.x >> 3) * 256;

  const u16* qkv_b = qkv + (size_t)b * NTOK * H3;
  const u16* vt_bh = vT + (size_t)bh * (size_t)DHEAD * NTOK;
  const int kcol = DIMD + h * DHEAD;
  const int csw = (c & 7) << 4;

  // Q B-frags: qf[ks] = Q[t0+w*32+c][ks*16 + h32*8 .. +7]
  bf16v8 qf[16];
  {
    const u16* qrow = qkv_b + (size_t)(t0 + w * 32 + c) * H3 + h * DHEAD + h32 * 8;
#pragma unroll
    for (int ks = 0; ks < 16; ks++)
      qf[ks] = *reinterpret_cast<const bf16v8*>(qrow + ks * 16);
  }

  f32x16 o[8];
#pragma unroll
  for (int dt = 0; dt < 8; dt++)
#pragma unroll
    for (int r = 0; r < 16; r++) o[dt][r] = 0.f;
  float m = -1e30f, l = 0.f;

  auto stage = [&](int kt) {
    const int buf = kt & 1;
    const int kt0 = kt * KVB;
    // K: 32 rows x 512B = 1024 chunks
#pragma unroll
    for (int i = 0; i < 2; i++) {
      const int q = i * 512 + tid;
      const int row = q >> 5;
      const int cb = ((q & 31) * 16) ^ ((row & 7) << 4);
      gload16(qkv_b + (size_t)(kt0 + row) * H3 + kcol + (cb >> 1),
              (char*)&Ks[buf][0] + (size_t)q * 16);
    }
    // V: 128 rows x 128B; row rr = {d=rr | d=rr+128} x 32 toks
#pragma unroll
    for (int i = 0; i < 2; i++) {
      const int q = i * 512 + tid;
      const int rr = q >> 3;
      const int p = ((q & 7) * 16) ^ ((rr & 7) << 4);
      const int d = rr + ((p >> 6) << 7);
      gload16(vt_bh + (size_t)d * NTOK + kt0 + ((p & 63) >> 1),
              (char*)&Vs[buf][0] + (size_t)q * 16);
    }
  };

  stage(0);

  for (int kt = 0; kt < NKT; kt++) {
    __syncthreads();            // tile kt staged; all waves done with kt-1
    if (kt + 1 < NKT) stage(kt + 1);

    const char* kb = (const char*)&Ks[kt & 1][0];
    const char* vb = (const char*)&Vs[kt & 1][0];

    // ---- S^T = K Q^T : lane holds 16 of 32 scores for q-row c ----
    f32x16 st;
#pragma unroll
    for (int r = 0; r < 16; r++) st[r] = 0.f;
    const char* krow = kb + c * 512;
    __builtin_amdgcn_s_setprio(1);
#pragma unroll
    for (int ks = 0; ks < 16; ks++) {
      const bf16v8 kf =
          *reinterpret_cast<const bf16v8*>(krow + ((ks * 32 + h32 * 16) ^ csw));
      st = __builtin_amdgcn_mfma_f32_32x32x16_bf16(kf, qf[ks], st, 0, 0, 0);
    }
    __builtin_amdgcn_s_setprio(0);

    // ---- lane-local online softmax (defer-max THR=8) ----
    float mx = st[0];
#pragma unroll
    for (int r = 1; r < 16; r++) mx = fmaxf(mx, st[r]);
    mx = fmaxf(mx, __shfl_xor(mx, 32, 64));
    const float pm = mx * 0.03125f;
    if (__any(pm > m + 8.f)) {
      const float mn = fmaxf(m, pm);
      const float corr = __expf(m - mn);
      m = mn; l *= corr;
#pragma unroll
      for (int dt = 0; dt < 8; dt++)
#pragma unroll
        for (int r = 0; r < 16; r++) o[dt][r] *= corr;
    }
    float sum = 0.f;
#pragma unroll
    for (int r = 0; r < 16; r++) {
      const float p = __expf(st[r] * 0.03125f - m);
      st[r] = p; sum += p;
    }
    sum += __shfl_xor(sum, 32, 64);
    l += sum;

    // ---- P -> bf16 B-frags (lane^32 exchange) + PV ----
#pragma unroll
    for (int s = 0; s < 2; s++) {
      const int rb = s * 8;
      float z[4];
#pragma unroll
      for (int k = 0; k < 4; k++) {
        const float y = h32 ? st[rb + k] : st[rb + 4 + k];  // send partner's need
        z[k] = __shfl_xor(y, 32, 64);
      }
      union { u16 u[8]; bf16v8 v; } pb;
#pragma unroll
      for (int k = 0; k < 4; k++) {
        pb.u[k]     = f2bf(h32 ? z[k] : st[rb + k]);
        pb.u[4 + k] = f2bf(h32 ? st[rb + 4 + k] : z[k]);
      }

      __builtin_amdgcn_s_setprio(1);
#pragma unroll
      for (int dt = 0; dt < 8; dt++) {
        const int rr = (dt & 3) * 32 + c;
        const int byte = (((dt >> 2) * 64 + s * 32 + h32 * 16)) ^ csw;
        const bf16v8 vf = *reinterpret_cast<const bf16v8*>(vb + rr * 128 + byte);
        o[dt] = __builtin_amdgcn_mfma_f32_32x32x16_bf16(vf, pb.v, o[dt], 0, 0, 0);
      }
      __builtin_amdgcn_s_setprio(0);
    }
  }

  // ---- epilogue: O^T/l -> obuf ----
  const float rl = 1.f / l;
  u16* orow = obuf + (size_t)(b * NTOK + t0 + w * 32 + c) * DIMD + h * DHEAD;
#pragma unroll
  for (int dt = 0; dt < 8; dt++) {
#pragma unroll
    for (int rq = 0; rq < 4; rq++) {
      ushort4 v4;
      v4.x = f2bf(o[dt][rq * 4 + 0] * rl);
      v4.y = f2bf(o[dt][rq * 4 + 1] * rl);
      v4.z = f2bf(o[dt][rq * 4 + 2] * rl);
      v4.w = f2bf(o[dt][rq * 4 + 3] * rl);
      *reinterpret_cast<ushort4*>(orow + dt * 32 + rq * 8 + h32 * 4) = v4;
    }
  }
}

// ---------------- GEMM v2: C[M,N] = A[M,K]*Bt[N,K]^T (bf16, fp32 acc) ------
// 2-phase double-buffered LDS: stage(next) issued BEFORE the MFMA of the
// current tile; ONE barrier per K-step. EPI: 0 bf16; 2 fp32 resid+=;
// 3 gelu; 4 conv epilogue.
template <int EPI>
__global__ __launch_bounds__(256) void gemm_bt(
    const u16* __restrict__ A, int lda,
    const u16* __restrict__ Bt, int ldb,
    int K, void* __restrict__ Cp, int ldc,
    const float* __restrict__ bias, const float* __restrict__ extra,
    float scale) {
  __shared__ __align__(16) u16 As[2][128 * 32];
  __shared__ __align__(16) u16 Bs[2][128 * 32];
  const int tid = threadIdx.x;
  const int bm = blockIdx.x, bn = blockIdx.y;

  const int c0 = tid, c1 = tid + 256;
  const u16* Ab = A + (size_t)(bm * 128) * lda;
  const u16* Bb = Bt + (size_t)(bn * 128) * ldb;
  const size_t a0 = (size_t)(c0 >> 2) * lda + (c0 & 3) * 8;
  const size_t a1 = (size_t)(c1 >> 2) * lda + (c1 & 3) * 8;
  const size_t b0 = (size_t)(c0 >> 2) * ldb + (c0 & 3) * 8;
  const size_t b1 = (size_t)(c1 >> 2) * ldb + (c1 & 3) * 8;

  const int lane = tid & 63;
  const int wv = tid >> 6;
  const int wm = (wv >> 1) * 64;
  const int wn = (wv & 1) * 64;
  const int fr = lane & 15;
  const int fk = (lane >> 4) * 8;

  auto stage = [&](int k0, int buf) {
    gload16(Ab + a0 + k0, &As[buf][0] + (size_t)c0 * 8);
    gload16(Ab + a1 + k0, &As[buf][0] + (size_t)c1 * 8);
    gload16(Bb + b0 + k0, &Bs[buf][0] + (size_t)c0 * 8);
    gload16(Bb + b1 + k0, &Bs[buf][0] + (size_t)c1 * 8);
  };

  f32v4 acc[4][4];
#pragma unroll
  for (int m = 0; m < 4; m++)
#pragma unroll
    for (int n = 0; n < 4; n++) acc[m][n] = (f32v4){0.f, 0.f, 0.f, 0.f};

  stage(0, 0);
  __syncthreads();               // tile 0 resident

  int buf = 0;
  for (int k0 = 0; k0 < K; k0 += 32) {
    if (k0 + 32 < K) stage(k0 + 32, buf ^ 1);   // prefetch overlaps MFMA

    bf16v8 af[4], bq[4];
#pragma unroll
    for (int m = 0; m < 4; m++)
      af[m] = *reinterpret_cast<const bf16v8*>(&As[buf][(wm + m * 16 + fr) * 32 + fk]);
#pragma unroll
    for (int n = 0; n < 4; n++)
      bq[n] = *reinterpret_cast<const bf16v8*>(&Bs[buf][(wn + n * 16 + fr) * 32 + fk]);
#pragma unroll
    for (int m = 0; m < 4; m++)
#pragma unroll
      for (int n = 0; n < 4; n++)
        acc[m][n] =
            __builtin_amdgcn_mfma_f32_16x16x32_bf16(af[m], bq[n], acc[m][n], 0, 0, 0);

    __syncthreads();             // drains prefetch; next iter reads buf^1
    buf ^= 1;
  }

  const int rbase = bm * 128 + wm + (lane >> 4) * 4;
  const int cbase = bn * 128 + wn + fr;
#pragma unroll
  for (int m = 0; m < 4; m++) {
#pragma unroll
    for (int n = 0; n < 4; n++) {
      const int col = cbase + n * 16;
#pragma unroll
      for (int j = 0; j < 4; j++) {
        const int rowi = rbase + m * 16 + j;
        const float v = acc[m][n][j];
        if (EPI == 0) {
          ((u16*)Cp)[(size_t)rowi * ldc + col] = f2bf(v);
        } else if (EPI == 2) {
          float* p = (float*)Cp + (size_t)rowi * ldc + col;
          *p += v + bias[col];
        } else if (EPI == 3) {
          float t = v + bias[col];
          t = 0.5f * t * (1.f + erff(t * 0.70710678118654752f));
          ((u16*)Cp)[(size_t)rowi * ldc + col] = f2bf(t);
        } else {
          ((float*)Cp)[(size_t)rowi * ldc + col] =
              v + bias[col] + extra[(size_t)(rowi % NTOK) * DIMD + col];
        }
      }
    }
  }
}

// ---------------------------------------------------------------------------
// workspace layout (bytes) — peak ~158 MB
// ---------------------------------------------------------------------------
#define SZ_QKVT ((size_t)H3 * DIMD * 2)
#define SZ_OUTT ((size_t)DIMD * DIMD * 2)
#define SZ_FC1T ((size_t)MLPH * DIMD * 2)
#define SZ_FC2T ((size_t)DIMD * MLPH * 2)
#define SZ_CONVW ((size_t)DIMD * 256 * 2)
#define SZ_X ((size_t)TTOT * DIMD * 4)
#define SZ_XO ((size_t)TTOT * DIMD * 2)            // x1 | obuf
#define SZ_BIGA ((size_t)TTOT * H3 * 2 + (size_t)8 * DHEAD * NTOK * 2) // qkv+vT | hbuf | patchA

#define OFF_QKVT ((size_t)0)
#define OFF_OUTT (OFF_QKVT + SZ_QKVT)
#define OFF_FC1T (OFF_OUTT + SZ_OUTT)
#define OFF_FC2T (OFF_FC1T + SZ_FC1T)
#define OFF_CONVW (OFF_FC2T + SZ_FC2T)
#define OFF_X (OFF_CONVW + SZ_CONVW)
#define OFF_XO (OFF_X + SZ_X)
#define OFF_BIGA (OFF_XO + SZ_XO)
#define WS_NEED (OFF_BIGA + SZ_BIGA)

extern "C" void kernel_launch(void* const* d_in, const int* in_sizes, int n_in,
                              void* d_out, int out_size, void* d_ws, size_t ws_size,
                              hipStream_t stream) {
  const float* img = (const float*)d_in[0];
  const float* conv_w = (const float*)d_in[1];
  const float* conv_b = (const float*)d_in[2];
  const float* pos = (const float*)d_in[3];
  const float* ln1_g = (const float*)d_in[4];
  const float* ln1_b = (const float*)d_in[5];
  const float* qkv_w = (const float*)d_in[6];
  const float* out_w = (const float*)d_in[7];
  const float* out_b = (const float*)d_in[8];
  const float* ln2_g = (const float*)d_in[9];
  const float* ln2_b = (const float*)d_in[10];
  const float* fc1_w = (const float*)d_in[11];
  const float* fc1_b = (const float*)d_in[12];
  const float* fc2_w = (const float*)d_in[13];
  const float* fc2_b = (const float*)d_in[14];
  const float* lnf_g = (const float*)d_in[15];
  const float* lnf_b = (const float*)d_in[16];
  float* out = (float*)d_out;

  if (ws_size < WS_NEED) return;

  char* ws = (char*)d_ws;
  u16* qkvT = (u16*)(ws + OFF_QKVT);
  u16* outT = (u16*)(ws + OFF_OUTT);
  u16* fc1T = (u16*)(ws + OFF_FC1T);
  u16* fc2T = (u16*)(ws + OFF_FC2T);
  u16* convW = (u16*)(ws + OFF_CONVW);
  float* x = (float*)(ws + OFF_X);
  u16* x1 = (u16*)(ws + OFF_XO);
  u16* obuf = (u16*)(ws + OFF_XO);     // aliased with x1 (disjoint lifetime)
  u16* qkv = (u16*)(ws + OFF_BIGA);
  u16* vT = (u16*)(ws + OFF_BIGA + (size_t)TTOT * H3 * 2);
  u16* hbuf = (u16*)(ws + OFF_BIGA);   // aliased (MLP phase)
  u16* patchA = (u16*)(ws + OFF_BIGA); // aliased (pre-layer phase)

  const dim3 tb(32, 8);

  // ---- patch embed ----
  convert_bf16<<<1024, 256, 0, stream>>>(conv_w, convW, DIMD * 256);
  patch_extract<<<TTOT, 256, 0, stream>>>(img, patchA);
  gemm_bt<4><<<dim3(TTOT / 128, DIMD / 128, 1), 256, 0, stream>>>(
      patchA, 256, convW, 256, 256, x, DIMD, conv_b, pos, 1.f);

  for (int l = 0; l < NLAYER; l++) {
    transpose_w<<<dim3(H3 / 32, DIMD / 32, 1), tb, 0, stream>>>(
        qkv_w + (size_t)l * DIMD * H3, qkvT, DIMD, H3);
    transpose_w<<<dim3(DIMD / 32, DIMD / 32, 1), tb, 0, stream>>>(
        out_w + (size_t)l * DIMD * DIMD, outT, DIMD, DIMD);
    transpose_w<<<dim3(MLPH / 32, DIMD / 32, 1), tb, 0, stream>>>(
        fc1_w + (size_t)l * DIMD * MLPH, fc1T, DIMD, MLPH);
    transpose_w<<<dim3(DIMD / 32, MLPH / 32, 1), tb, 0, stream>>>(
        fc2_w + (size_t)l * MLPH * DIMD, fc2T, MLPH, DIMD);

    // LN1 -> x1 (bf16)
    ln_kernel<0><<<TTOT, 256, 0, stream>>>(x, ln1_g + l * DIMD, ln1_b + l * DIMD, x1);
    // QKV
    gemm_bt<0><<<dim3(TTOT / 128, H3 / 128, 1), 256, 0, stream>>>(
        x1, DIMD, qkvT, DIMD, DIMD, qkv, H3, nullptr, nullptr, 1.f);
    // V -> vT
    transpose_v<<<dim3(NTOK / 32, DHEAD / 32, 8), tb, 0, stream>>>(qkv, vT);

    // fused attention -> obuf
    flash_attn<<<dim3(18 * 8, 1, 1), 512, 0, stream>>>(qkv, vT, obuf);

    // x += o @ out_w + out_b
    gemm_bt<2><<<dim3(TTOT / 128, DIMD / 128, 1), 256, 0, stream>>>(
        obuf, DIMD, outT, DIMD, DIMD, x, DIMD, out_b + l * DIMD, nullptr, 1.f);
    // LN2 -> x1
    ln_kernel<0><<<TTOT, 256, 0, stream>>>(x, ln2_g + l * DIMD, ln2_b + l * DIMD, x1);
    // h = gelu(x1 @ fc1 + b)
    gemm_bt<3><<<dim3(TTOT / 128, MLPH / 128, 1), 256, 0, stream>>>(
        x1, DIMD, fc1T, DIMD, DIMD, hbuf, MLPH, fc1_b + l * MLPH, nullptr, 1.f);
    // x += h @ fc2 + b
    gemm_bt<2><<<dim3(TTOT / 128, DIMD / 128, 1), 256, 0, stream>>>(
        hbuf, MLPH, fc2T, MLPH, MLPH, x, DIMD, fc2_b + l * DIMD, nullptr, 1.f);
  }

  ln_kernel<1><<<TTOT, 256, 0, stream>>>(x, lnf_g, lnf_b, out);
}

// Round 22
// 2839.300 us; speedup vs baseline: 1.0621x; 1.0091x over previous
//
#include <hip/hip_runtime.h>

// ---------------------------------------------------------------------------
// ViT forward on MI355X. bf16 MFMA GEMMs (2-phase double-buffered,
// __launch_bounds__(256,4) -> 4 blocks/CU) + fused flash attn v8.
// ---------------------------------------------------------------------------

typedef unsigned short u16;
typedef __bf16 bf16v8 __attribute__((ext_vector_type(8)));
typedef float f32v4 __attribute__((ext_vector_type(4)));
typedef float f32x16 __attribute__((ext_vector_type(16)));

#define NTOK   4608
#define TTOT   9216
#define DIMD   1024
#define H3     3072
#define MLPH   4096
#define NHEAD  4
#define DHEAD  256
#define NLAYER 4
#define KVB    32
#define NKT    (NTOK / KVB)   // 144

__device__ __forceinline__ u16 f2bf(float f) {
  unsigned u = __float_as_uint(f);
  u += 0x7fffu + ((u >> 16) & 1u);   // RNE
  return (u16)(u >> 16);
}
__device__ __forceinline__ float bf2f(u16 b) {
  return __uint_as_float(((unsigned)b) << 16);
}
__device__ __forceinline__ void gload16(const void* g, void* l) {
  __builtin_amdgcn_global_load_lds((__attribute__((address_space(1))) void*)g,
                                   (__attribute__((address_space(3))) void*)l,
                                   16, 0, 0);
}

// ---------------- weight transpose fp32(R,C) -> bf16(C,R) ----------------
__global__ __launch_bounds__(256) void transpose_w(
    const float* __restrict__ src, u16* __restrict__ dst, int R, int C) {
  __shared__ float tile[32][33];
  const int c0 = blockIdx.x * 32, r0 = blockIdx.y * 32;
  const int tx = threadIdx.x, ty = threadIdx.y;
#pragma unroll
  for (int i = 0; i < 32; i += 8)
    tile[ty + i][tx] = src[(size_t)(r0 + ty + i) * C + c0 + tx];
  __syncthreads();
#pragma unroll
  for (int i = 0; i < 32; i += 8)
    dst[(size_t)(c0 + ty + i) * R + r0 + tx] = f2bf(tile[tx][ty + i]);
}

__global__ __launch_bounds__(256) void convert_bf16(
    const float* __restrict__ src, u16* __restrict__ dst, int n) {
  int i = blockIdx.x * 256 + threadIdx.x;
  if (i < n) dst[i] = f2bf(src[i]);
}

// ---------------- patch extraction: img -> A[9216][256] bf16 ----------------
__global__ __launch_bounds__(256) void patch_extract(
    const float* __restrict__ img, u16* __restrict__ A) {
  const int t = blockIdx.x;
  const int k = threadIdx.x;
  const int b = t / NTOK, r = t % NTOK;
  const int d = r / 576, r2 = r % 576;
  const int hh = r2 / 24, ww = r2 % 24;
  const int ci = k >> 7, k2 = k & 127;
  const int kd = k2 >> 6, k3 = k2 & 63;
  const int kh = k3 >> 3, kw = k3 & 7;
  const size_t idx =
      ((size_t)((b * 2 + ci) * 16 + (2 * d + kd))) * (192 * 192) +
      (size_t)(8 * hh + kh) * 192 + (8 * ww + kw);
  A[(size_t)t * 256 + k] = f2bf(img[idx]);
}

// ---------------- LayerNorm (row=1024). OUTF32: 1 -> fp32, 0 -> bf16 --------
template <int OUTF32>
__global__ __launch_bounds__(256) void ln_kernel(
    const float* __restrict__ x, const float* __restrict__ g,
    const float* __restrict__ bta, void* __restrict__ out) {
  const size_t row = blockIdx.x;
  const int t = threadIdx.x;
  const float4 v = ((const float4*)(x + row * DIMD))[t];
  float s = v.x + v.y + v.z + v.w;
  float ss = v.x * v.x + v.y * v.y + v.z * v.z + v.w * v.w;
#pragma unroll
  for (int o = 32; o; o >>= 1) {
    s += __shfl_xor(s, o, 64);
    ss += __shfl_xor(ss, o, 64);
  }
  __shared__ float sh[8];
  if ((t & 63) == 0) { sh[t >> 6] = s; sh[4 + (t >> 6)] = ss; }
  __syncthreads();
  s = sh[0] + sh[1] + sh[2] + sh[3];
  ss = sh[4] + sh[5] + sh[6] + sh[7];
  const float mu = s * (1.f / DIMD);
  const float rs = rsqrtf(ss * (1.f / DIMD) - mu * mu + 1e-5f);
  const float4 gg = ((const float4*)g)[t];
  const float4 bb = ((const float4*)bta)[t];
  const float y0 = (v.x - mu) * rs * gg.x + bb.x;
  const float y1 = (v.y - mu) * rs * gg.y + bb.y;
  const float y2 = (v.z - mu) * rs * gg.z + bb.z;
  const float y3 = (v.w - mu) * rs * gg.w + bb.w;
  if (OUTF32) {
    float4 o4; o4.x = y0; o4.y = y1; o4.z = y2; o4.w = y3;
    ((float4*)out)[row * 256 + t] = o4;
  } else {
    ushort4 o4;
    o4.x = f2bf(y0); o4.y = f2bf(y1); o4.z = f2bf(y2); o4.w = f2bf(y3);
    ((ushort4*)out)[row * 256 + t] = o4;
  }
}

// ---------------- transpose V slice of qkv -> vT[b][h][256][4608] -----------
__global__ __launch_bounds__(256) void transpose_v(
    const u16* __restrict__ qkv, u16* __restrict__ vT) {
  const int bh = blockIdx.z, b = bh >> 2, h = bh & 3;
  const u16* src = qkv + (size_t)b * NTOK * H3 + 2048 + h * DHEAD;
  u16* dst = vT + (size_t)bh * DHEAD * NTOK;
  __shared__ u16 tile[32][33];
  const int t0 = blockIdx.x * 32, d0 = blockIdx.y * 32;
  const int tx = threadIdx.x, ty = threadIdx.y;
#pragma unroll
  for (int i = 0; i < 32; i += 8)
    tile[ty + i][tx] = src[(size_t)(t0 + ty + i) * H3 + d0 + tx];
  __syncthreads();
#pragma unroll
  for (int i = 0; i < 32; i += 8)
    dst[(size_t)(d0 + ty + i) * NTOK + t0 + tx] = tile[tx][ty + i];
}

// ---------------------------------------------------------------------------
// Fused flash attention v8 (measured best: 333 us/launch).
// Grid: 144 = 18 qtiles x 8 bh. 512 thr = 8 waves; wave owns 32 q-rows
// (q-row = lane&31 = c; partner c^32 shares the row). KVB=32, double-buffered
// K[32][512B] + V[128][128B] (row rr = d=rr|d=rr+128), XOR swizzle
// ((row&7)<<4) via pre-swizzled global source (rule 21).
// ---------------------------------------------------------------------------
__global__ __launch_bounds__(512, 2) void flash_attn(
    const u16* __restrict__ qkv, const u16* __restrict__ vT,
    u16* __restrict__ obuf) {
  __shared__ __align__(16) u16 Ks[2][KVB * 256];  // 16 KB each
  __shared__ __align__(16) u16 Vs[2][128 * 64];   // 16 KB each

  const int tid = threadIdx.x;
  const int lane = tid & 63, w = tid >> 6;
  const int c = lane & 31, h32 = lane >> 5;
  const int bh = blockIdx.x & 7, b = bh >> 2, h = bh & 3;
  const int t0 = (blockIdx.x >> 3) * 256;

  const u16* qkv_b = qkv + (size_t)b * NTOK * H3;
  const u16* vt_bh = vT + (size_t)bh * (size_t)DHEAD * NTOK;
  const int kcol = DIMD + h * DHEAD;
  const int csw = (c & 7) << 4;

  // Q B-frags: qf[ks] = Q[t0+w*32+c][ks*16 + h32*8 .. +7]
  bf16v8 qf[16];
  {
    const u16* qrow = qkv_b + (size_t)(t0 + w * 32 + c) * H3 + h * DHEAD + h32 * 8;
#pragma unroll
    for (int ks = 0; ks < 16; ks++)
      qf[ks] = *reinterpret_cast<const bf16v8*>(qrow + ks * 16);
  }

  f32x16 o[8];
#pragma unroll
  for (int dt = 0; dt < 8; dt++)
#pragma unroll
    for (int r = 0; r < 16; r++) o[dt][r] = 0.f;
  float m = -1e30f, l = 0.f;

  auto stage = [&](int kt) {
    const int buf = kt & 1;
    const int kt0 = kt * KVB;
    // K: 32 rows x 512B = 1024 chunks
#pragma unroll
    for (int i = 0; i < 2; i++) {
      const int q = i * 512 + tid;
      const int row = q >> 5;
      const int cb = ((q & 31) * 16) ^ ((row & 7) << 4);
      gload16(qkv_b + (size_t)(kt0 + row) * H3 + kcol + (cb >> 1),
              (char*)&Ks[buf][0] + (size_t)q * 16);
    }
    // V: 128 rows x 128B; row rr = {d=rr | d=rr+128} x 32 toks
#pragma unroll
    for (int i = 0; i < 2; i++) {
      const int q = i * 512 + tid;
      const int rr = q >> 3;
      const int p = ((q & 7) * 16) ^ ((rr & 7) << 4);
      const int d = rr + ((p >> 6) << 7);
      gload16(vt_bh + (size_t)d * NTOK + kt0 + ((p & 63) >> 1),
              (char*)&Vs[buf][0] + (size_t)q * 16);
    }
  };

  stage(0);

  for (int kt = 0; kt < NKT; kt++) {
    __syncthreads();            // tile kt staged; all waves done with kt-1
    if (kt + 1 < NKT) stage(kt + 1);

    const char* kb = (const char*)&Ks[kt & 1][0];
    const char* vb = (const char*)&Vs[kt & 1][0];

    // ---- S^T = K Q^T : lane holds 16 of 32 scores for q-row c ----
    f32x16 st;
#pragma unroll
    for (int r = 0; r < 16; r++) st[r] = 0.f;
    const char* krow = kb + c * 512;
    __builtin_amdgcn_s_setprio(1);
#pragma unroll
    for (int ks = 0; ks < 16; ks++) {
      const bf16v8 kf =
          *reinterpret_cast<const bf16v8*>(krow + ((ks * 32 + h32 * 16) ^ csw));
      st = __builtin_amdgcn_mfma_f32_32x32x16_bf16(kf, qf[ks], st, 0, 0, 0);
    }
    __builtin_amdgcn_s_setprio(0);

    // ---- lane-local online softmax (defer-max THR=8) ----
    float mx = st[0];
#pragma unroll
    for (int r = 1; r < 16; r++) mx = fmaxf(mx, st[r]);
    mx = fmaxf(mx, __shfl_xor(mx, 32, 64));
    const float pm = mx * 0.03125f;
    if (__any(pm > m + 8.f)) {
      const float mn = fmaxf(m, pm);
      const float corr = __expf(m - mn);
      m = mn; l *= corr;
#pragma unroll
      for (int dt = 0; dt < 8; dt++)
#pragma unroll
        for (int r = 0; r < 16; r++) o[dt][r] *= corr;
    }
    float sum = 0.f;
#pragma unroll
    for (int r = 0; r < 16; r++) {
      const float p = __expf(st[r] * 0.03125f - m);
      st[r] = p; sum += p;
    }
    sum += __shfl_xor(sum, 32, 64);
    l += sum;

    // ---- P -> bf16 B-frags (lane^32 exchange) + PV ----
#pragma unroll
    for (int s = 0; s < 2; s++) {
      const int rb = s * 8;
      float z[4];
#pragma unroll
      for (int k = 0; k < 4; k++) {
        const float y = h32 ? st[rb + k] : st[rb + 4 + k];  // send partner's need
        z[k] = __shfl_xor(y, 32, 64);
      }
      union { u16 u[8]; bf16v8 v; } pb;
#pragma unroll
      for (int k = 0; k < 4; k++) {
        pb.u[k]     = f2bf(h32 ? z[k] : st[rb + k]);
        pb.u[4 + k] = f2bf(h32 ? st[rb + 4 + k] : z[k]);
      }

      __builtin_amdgcn_s_setprio(1);
#pragma unroll
      for (int dt = 0; dt < 8; dt++) {
        const int rr = (dt & 3) * 32 + c;
        const int byte = (((dt >> 2) * 64 + s * 32 + h32 * 16)) ^ csw;
        const bf16v8 vf = *reinterpret_cast<const bf16v8*>(vb + rr * 128 + byte);
        o[dt] = __builtin_amdgcn_mfma_f32_32x32x16_bf16(vf, pb.v, o[dt], 0, 0, 0);
      }
      __builtin_amdgcn_s_setprio(0);
    }
  }

  // ---- epilogue: O^T/l -> obuf ----
  const float rl = 1.f / l;
  u16* orow = obuf + (size_t)(b * NTOK + t0 + w * 32 + c) * DIMD + h * DHEAD;
#pragma unroll
  for (int dt = 0; dt < 8; dt++) {
#pragma unroll
    for (int rq = 0; rq < 4; rq++) {
      ushort4 v4;
      v4.x = f2bf(o[dt][rq * 4 + 0] * rl);
      v4.y = f2bf(o[dt][rq * 4 + 1] * rl);
      v4.z = f2bf(o[dt][rq * 4 + 2] * rl);
      v4.w = f2bf(o[dt][rq * 4 + 3] * rl);
      *reinterpret_cast<ushort4*>(orow + dt * 32 + rq * 8 + h32 * 4) = v4;
    }
  }
}

// ---------------- GEMM v2b: 2-phase dbuf + 4 blocks/CU ----------------------
// __launch_bounds__(256, 4): 32 KB LDS/block -> 4 blocks fit (128 KB);
// reg budget 128/thread (measured ~76-110 for this kernel). 4 co-resident
// blocks overlap each other's per-iter barrier drains (m114 mechanism).
// EPI: 0 bf16; 2 fp32 resid+=; 3 gelu; 4 conv epilogue.
template <int EPI>
__global__ __launch_bounds__(256, 4) void gemm_bt(
    const u16* __restrict__ A, int lda,
    const u16* __restrict__ Bt, int ldb,
    int K, void* __restrict__ Cp, int ldc,
    const float* __restrict__ bias, const float* __restrict__ extra,
    float scale) {
  __shared__ __align__(16) u16 As[2][128 * 32];
  __shared__ __align__(16) u16 Bs[2][128 * 32];
  const int tid = threadIdx.x;
  const int bm = blockIdx.x, bn = blockIdx.y;

  const int c0 = tid, c1 = tid + 256;
  const u16* Ab = A + (size_t)(bm * 128) * lda;
  const u16* Bb = Bt + (size_t)(bn * 128) * ldb;
  const size_t a0 = (size_t)(c0 >> 2) * lda + (c0 & 3) * 8;
  const size_t a1 = (size_t)(c1 >> 2) * lda + (c1 & 3) * 8;
  const size_t b0 = (size_t)(c0 >> 2) * ldb + (c0 & 3) * 8;
  const size_t b1 = (size_t)(c1 >> 2) * ldb + (c1 & 3) * 8;

  const int lane = tid & 63;
  const int wv = tid >> 6;
  const int wm = (wv >> 1) * 64;
  const int wn = (wv & 1) * 64;
  const int fr = lane & 15;
  const int fk = (lane >> 4) * 8;

  auto stage = [&](int k0, int buf) {
    gload16(Ab + a0 + k0, &As[buf][0] + (size_t)c0 * 8);
    gload16(Ab + a1 + k0, &As[buf][0] + (size_t)c1 * 8);
    gload16(Bb + b0 + k0, &Bs[buf][0] + (size_t)c0 * 8);
    gload16(Bb + b1 + k0, &Bs[buf][0] + (size_t)c1 * 8);
  };

  f32v4 acc[4][4];
#pragma unroll
  for (int m = 0; m < 4; m++)
#pragma unroll
    for (int n = 0; n < 4; n++) acc[m][n] = (f32v4){0.f, 0.f, 0.f, 0.f};

  stage(0, 0);
  __syncthreads();               // tile 0 resident

  int buf = 0;
  for (int k0 = 0; k0 < K; k0 += 32) {
    if (k0 + 32 < K) stage(k0 + 32, buf ^ 1);   // prefetch overlaps MFMA

    bf16v8 af[4], bq[4];
#pragma unroll
    for (int m = 0; m < 4; m++)
      af[m] = *reinterpret_cast<const bf16v8*>(&As[buf][(wm + m * 16 + fr) * 32 + fk]);
#pragma unroll
    for (int n = 0; n < 4; n++)
      bq[n] = *reinterpret_cast<const bf16v8*>(&Bs[buf][(wn + n * 16 + fr) * 32 + fk]);
#pragma unroll
    for (int m = 0; m < 4; m++)
#pragma unroll
      for (int n = 0; n < 4; n++)
        acc[m][n] =
            __builtin_amdgcn_mfma_f32_16x16x32_bf16(af[m], bq[n], acc[m][n], 0, 0, 0);

    __syncthreads();             // drains prefetch; next iter reads buf^1
    buf ^= 1;
  }

  const int rbase = bm * 128 + wm + (lane >> 4) * 4;
  const int cbase = bn * 128 + wn + fr;
#pragma unroll
  for (int m = 0; m < 4; m++) {
#pragma unroll
    for (int n = 0; n < 4; n++) {
      const int col = cbase + n * 16;
#pragma unroll
      for (int j = 0; j < 4; j++) {
        const int rowi = rbase + m * 16 + j;
        const float v = acc[m][n][j];
        if (EPI == 0) {
          ((u16*)Cp)[(size_t)rowi * ldc + col] = f2bf(v);
        } else if (EPI == 2) {
          float* p = (float*)Cp + (size_t)rowi * ldc + col;
          *p += v + bias[col];
        } else if (EPI == 3) {
          float t = v + bias[col];
          t = 0.5f * t * (1.f + erff(t * 0.70710678118654752f));
          ((u16*)Cp)[(size_t)rowi * ldc + col] = f2bf(t);
        } else {
          ((float*)Cp)[(size_t)rowi * ldc + col] =
              v + bias[col] + extra[(size_t)(rowi % NTOK) * DIMD + col];
        }
      }
    }
  }
}

// ---------------------------------------------------------------------------
// workspace layout (bytes) — peak ~158 MB
// ---------------------------------------------------------------------------
#define SZ_QKVT ((size_t)H3 * DIMD * 2)
#define SZ_OUTT ((size_t)DIMD * DIMD * 2)
#define SZ_FC1T ((size_t)MLPH * DIMD * 2)
#define SZ_FC2T ((size_t)DIMD * MLPH * 2)
#define SZ_CONVW ((size_t)DIMD * 256 * 2)
#define SZ_X ((size_t)TTOT * DIMD * 4)
#define SZ_XO ((size_t)TTOT * DIMD * 2)            // x1 | obuf
#define SZ_BIGA ((size_t)TTOT * H3 * 2 + (size_t)8 * DHEAD * NTOK * 2) // qkv+vT | hbuf | patchA

#define OFF_QKVT ((size_t)0)
#define OFF_OUTT (OFF_QKVT + SZ_QKVT)
#define OFF_FC1T (OFF_OUTT + SZ_OUTT)
#define OFF_FC2T (OFF_FC1T + SZ_FC1T)
#define OFF_CONVW (OFF_FC2T + SZ_FC2T)
#define OFF_X (OFF_CONVW + SZ_CONVW)
#define OFF_XO (OFF_X + SZ_X)
#define OFF_BIGA (OFF_XO + SZ_XO)
#define WS_NEED (OFF_BIGA + SZ_BIGA)

extern "C" void kernel_launch(void* const* d_in, const int* in_sizes, int n_in,
                              void* d_out, int out_size, void* d_ws, size_t ws_size,
                              hipStream_t stream) {
  const float* img = (const float*)d_in[0];
  const float* conv_w = (const float*)d_in[1];
  const float* conv_b = (const float*)d_in[2];
  const float* pos = (const float*)d_in[3];
  const float* ln1_g = (const float*)d_in[4];
  const float* ln1_b = (const float*)d_in[5];
  const float* qkv_w = (const float*)d_in[6];
  const float* out_w = (const float*)d_in[7];
  const float* out_b = (const float*)d_in[8];
  const float* ln2_g = (const float*)d_in[9];
  const float* ln2_b = (const float*)d_in[10];
  const float* fc1_w = (const float*)d_in[11];
  const float* fc1_b = (const float*)d_in[12];
  const float* fc2_w = (const float*)d_in[13];
  const float* fc2_b = (const float*)d_in[14];
  const float* lnf_g = (const float*)d_in[15];
  const float* lnf_b = (const float*)d_in[16];
  float* out = (float*)d_out;

  if (ws_size < WS_NEED) return;

  char* ws = (char*)d_ws;
  u16* qkvT = (u16*)(ws + OFF_QKVT);
  u16* outT = (u16*)(ws + OFF_OUTT);
  u16* fc1T = (u16*)(ws + OFF_FC1T);
  u16* fc2T = (u16*)(ws + OFF_FC2T);
  u16* convW = (u16*)(ws + OFF_CONVW);
  float* x = (float*)(ws + OFF_X);
  u16* x1 = (u16*)(ws + OFF_XO);
  u16* obuf = (u16*)(ws + OFF_XO);     // aliased with x1 (disjoint lifetime)
  u16* qkv = (u16*)(ws + OFF_BIGA);
  u16* vT = (u16*)(ws + OFF_BIGA + (size_t)TTOT * H3 * 2);
  u16* hbuf = (u16*)(ws + OFF_BIGA);   // aliased (MLP phase)
  u16* patchA = (u16*)(ws + OFF_BIGA); // aliased (pre-layer phase)

  const dim3 tb(32, 8);

  // ---- patch embed ----
  convert_bf16<<<1024, 256, 0, stream>>>(conv_w, convW, DIMD * 256);
  patch_extract<<<TTOT, 256, 0, stream>>>(img, patchA);
  gemm_bt<4><<<dim3(TTOT / 128, DIMD / 128, 1), 256, 0, stream>>>(
      patchA, 256, convW, 256, 256, x, DIMD, conv_b, pos, 1.f);

  for (int l = 0; l < NLAYER; l++) {
    transpose_w<<<dim3(H3 / 32, DIMD / 32, 1), tb, 0, stream>>>(
        qkv_w + (size_t)l * DIMD * H3, qkvT, DIMD, H3);
    transpose_w<<<dim3(DIMD / 32, DIMD / 32, 1), tb, 0, stream>>>(
        out_w + (size_t)l * DIMD * DIMD, outT, DIMD, DIMD);
    transpose_w<<<dim3(MLPH / 32, DIMD / 32, 1), tb, 0, stream>>>(
        fc1_w + (size_t)l * DIMD * MLPH, fc1T, DIMD, MLPH);
    transpose_w<<<dim3(DIMD / 32, MLPH / 32, 1), tb, 0, stream>>>(
        fc2_w + (size_t)l * MLPH * DIMD, fc2T, MLPH, DIMD);

    // LN1 -> x1 (bf16)
    ln_kernel<0><<<TTOT, 256, 0, stream>>>(x, ln1_g + l * DIMD, ln1_b + l * DIMD, x1);
    // QKV
    gemm_bt<0><<<dim3(TTOT / 128, H3 / 128, 1), 256, 0, stream>>>(
        x1, DIMD, qkvT, DIMD, DIMD, qkv, H3, nullptr, nullptr, 1.f);
    // V -> vT
    transpose_v<<<dim3(NTOK / 32, DHEAD / 32, 8), tb, 0, stream>>>(qkv, vT);

    // fused attention -> obuf
    flash_attn<<<dim3(18 * 8, 1, 1), 512, 0, stream>>>(qkv, vT, obuf);

    // x += o @ out_w + out_b
    gemm_bt<2><<<dim3(TTOT / 128, DIMD / 128, 1), 256, 0, stream>>>(
        obuf, DIMD, outT, DIMD, DIMD, x, DIMD, out_b + l * DIMD, nullptr, 1.f);
    // LN2 -> x1
    ln_kernel<0><<<TTOT, 256, 0, stream>>>(x, ln2_g + l * DIMD, ln2_b + l * DIMD, x1);
    // h = gelu(x1 @ fc1 + b)
    gemm_bt<3><<<dim3(TTOT / 128, MLPH / 128, 1), 256, 0, stream>>>(
        x1, DIMD, fc1T, DIMD, DIMD, hbuf, MLPH, fc1_b + l * MLPH, nullptr, 1.f);
    // x += h @ fc2 + b
    gemm_bt<2><<<dim3(TTOT / 128, DIMD / 128, 1), 256, 0, stream>>>(
        hbuf, MLPH, fc2T, MLPH, MLPH, x, DIMD, fc2_b + l * DIMD, nullptr, 1.f);
  }

  ln_kernel<1><<<TTOT, 256, 0, stream>>>(x, lnf_g, lnf_b, out);
}